// Round 4
// baseline (8084.646 us; speedup 1.0000x reference)
//
#include <hip/hip_runtime.h>
#include <math.h>
#include <stdint.h>

#define TT   512
#define BB   64
#define EMBD 300
#define NU   512
#define G3   1536   // 3*UNITS

static constexpr size_t XW_FLOATS = (size_t)2 * TT * BB * G3;   // 100,663,296
static constexpr size_t HB_FLOATS = (size_t)2 * 2 * BB * NU;    //     131,072

// ------------- embedding gather + input GEMM: xw[dir][t][b][c] -------------
__global__ __launch_bounds__(256) void k_input_gemm(
    const int* __restrict__ tokens, const float* __restrict__ emb,
    const float* __restrict__ Wf, const float* __restrict__ bf,
    const float* __restrict__ Wb, const float* __restrict__ bb,
    float* __restrict__ xw) {
  __shared__ float As[8][72];   // [k][b]
  __shared__ float Bs[8][64];   // [k][n]
  __shared__ int tok[64];
  const int t = blockIdx.y;
  const int n0 = blockIdx.x * 64;
  const int dir = blockIdx.z;
  const float* W = dir ? Wb : Wf;
  const float* bias = dir ? bb : bf;           // row 0 = input bias
  float* out = xw + (size_t)dir * TT * BB * G3;
  const int tid = threadIdx.x;
  if (tid < 64) tok[tid] = tokens[(size_t)tid * TT + t];
  __syncthreads();
  const int tx = tid & 15, ty = tid >> 4;
  float4 c0 = {0,0,0,0}, c1 = {0,0,0,0}, c2 = {0,0,0,0}, c3 = {0,0,0,0};
  for (int kc = 0; kc < 38; ++kc) {
    const int k0 = kc * 8;
    if (tid < 128) {
      int kb = tid >> 4, nq = (tid & 15) * 4;
      float4 v = {0,0,0,0};
      if (k0 + kb < EMBD) v = *(const float4*)(W + (size_t)(k0 + kb) * G3 + n0 + nq);
      *(float4*)&Bs[kb][nq] = v;
    } else {
      int th = tid - 128;
      int b = th >> 1, kh = (th & 1) * 4;
      float4 v = {0,0,0,0};
      if (k0 + kh + 4 <= EMBD) v = *(const float4*)(emb + (size_t)tok[b] * EMBD + k0 + kh);
      As[kh + 0][b] = v.x; As[kh + 1][b] = v.y; As[kh + 2][b] = v.z; As[kh + 3][b] = v.w;
    }
    __syncthreads();
    #pragma unroll
    for (int kb = 0; kb < 8; ++kb) {
      float4 bv = *(const float4*)&Bs[kb][tx * 4];
      float4 av = *(const float4*)&As[kb][ty * 4];
      c0.x = fmaf(av.x, bv.x, c0.x); c0.y = fmaf(av.x, bv.y, c0.y);
      c0.z = fmaf(av.x, bv.z, c0.z); c0.w = fmaf(av.x, bv.w, c0.w);
      c1.x = fmaf(av.y, bv.x, c1.x); c1.y = fmaf(av.y, bv.y, c1.y);
      c1.z = fmaf(av.y, bv.z, c1.z); c1.w = fmaf(av.y, bv.w, c1.w);
      c2.x = fmaf(av.z, bv.x, c2.x); c2.y = fmaf(av.z, bv.y, c2.y);
      c2.z = fmaf(av.z, bv.z, c2.z); c2.w = fmaf(av.z, bv.w, c2.w);
      c3.x = fmaf(av.w, bv.x, c3.x); c3.y = fmaf(av.w, bv.y, c3.y);
      c3.z = fmaf(av.w, bv.z, c3.z); c3.w = fmaf(av.w, bv.w, c3.w);
    }
    __syncthreads();
  }
  float4 bi = *(const float4*)(bias + n0 + tx * 4);
  size_t base = ((size_t)t * BB + (size_t)ty * 4) * G3 + n0 + tx * 4;
  float4 o;
  o.x = c0.x + bi.x; o.y = c0.y + bi.y; o.z = c0.z + bi.z; o.w = c0.w + bi.w;
  *(float4*)(out + base) = o;
  o.x = c1.x + bi.x; o.y = c1.y + bi.y; o.z = c1.z + bi.z; o.w = c1.w + bi.w;
  *(float4*)(out + base + G3) = o;
  o.x = c2.x + bi.x; o.y = c2.y + bi.y; o.z = c2.z + bi.z; o.w = c2.w + bi.w;
  *(float4*)(out + base + 2 * G3) = o;
  o.x = c3.x + bi.x; o.y = c3.y + bi.y; o.z = c3.z + bi.z; o.w = c3.w + bi.w;
  *(float4*)(out + base + 3 * G3) = o;
}

// --------------------------- persistent GRU scan v5 ---------------------------
// Geometry = v1 (measured best): 256 blocks = dir(2) x bblk(8) x ublk(16),
// 1 block/CU, 32-unit slices, U register-resident (192 VGPRs, asm-pinned),
// 8 ksplits x 64k, 8 batches in regs, LDS reduction. Arithmetic bit-identical
// to v1 (absmax 9.77e-4 proven).
// SYNC v5: h-exchange via agent-scope atomic EXCHANGE (RMW). Device-scope RMWs
// cannot execute in the non-coherent per-XCD L2 -> they execute AT the LLC.
// Returning form (+asm pin of the old value) guarantees the vmcnt ack =
// "applied at LLC". After __syncthreads (drains all waves' RMW round-trips),
// a RELAXED flag RMW is ordered after the h data at the LLC.
// => NO release, NO buffer_wbl2 anywhere in the loop (v1/v4's ~8us/step cost).
// Reader path unchanged from v1/v4-proven relaxed agent atomic loads (LLC).
// out-store (nontemporal) + xw prefetch moved into the poll window so the
// pre-flag drain covers only the single h-exchange per thread.
__global__ __launch_bounds__(256, 1) void k_gru(
    const float* __restrict__ xw,
    const float* __restrict__ Uf, const float* __restrict__ Ub,
    const float* __restrict__ bf, const float* __restrict__ bb,
    float* __restrict__ hbuf, int* __restrict__ ctr,
    float* __restrict__ out, float* __restrict__ state) {
  __shared__ float hS[8][NU];          // h for this block's 8 batches
  __shared__ float red[3][8][8][32];   // [gate][batch][ksplit][unit]
  const int wg = blockIdx.x;
  const int dir = wg >> 7;
  const int bblk = (wg >> 4) & 7;
  const int ublk = wg & 15;
  const int u0 = ublk * 32, b0 = bblk * 8;
  const int gid = dir * 8 + bblk;
  int* flags = ctr + gid * 16;         // 16 member flags = one 64B line
  const int tid = threadIdx.x;
  const int u = tid & 31;              // local unit
  const int hi = tid >> 5;             // ksplit in compute, batch in epilogue
  const int kb0 = hi * 64;
  const float* xwd = xw + (size_t)dir * TT * BB * G3;
  const float* U = dir ? Ub : Uf;      // [k][c], c = gate*512 + unit
  const float* br = (dir ? bb : bf) + G3;   // row 1 = recurrent bias
  const float brz = br[u0 + u], brr = br[512 + u0 + u], brh = br[1024 + u0 + u];
  float* hb = hbuf + (size_t)dir * 2 * BB * NU;

  // ---- preload this thread's U slice into registers, then PIN ----
  float Uz_r[64], Ur_r[64], Uh_r[64];
  #pragma unroll
  for (int kk = 0; kk < 64; ++kk) {
    const float* row = U + (size_t)(kb0 + kk) * G3 + u0 + u;
    Uz_r[kk] = row[0];
    Ur_r[kk] = row[512];
    Uh_r[kk] = row[1024];
  }
  #pragma unroll
  for (int kk = 0; kk < 64; ++kk) {
    asm volatile("" : "+v"(Uz_r[kk]), "+v"(Ur_r[kk]), "+v"(Uh_r[kk]));
  }

  #pragma unroll
  for (int j = 0; j < 16; ++j) hS[hi][u + j * 32] = 0.f;   // h0 = 0
  __syncthreads();

  // preload step-0 gate pre-activations (batch = hi)
  float xz, xr, xh;
  {
    const int t0 = dir ? (TT - 1) : 0;
    const float* xp = xwd + ((size_t)t0 * BB + b0 + hi) * G3 + u0 + u;
    xz = xp[0]; xr = xp[512]; xh = xp[1024];
  }

  for (int s = 0; s < TT; ++s) {
    const int t = dir ? (TT - 1 - s) : s;
    float az[8], ar[8], ah[8];
    #pragma unroll
    for (int b = 0; b < 8; ++b) { az[b] = 0.f; ar[b] = 0.f; ah[b] = 0.f; }
    #pragma unroll
    for (int q = 0; q < 16; ++q) {
      #pragma unroll
      for (int b = 0; b < 8; ++b) {
        float4 hv = *(const float4*)&hS[b][kb0 + q * 4];   // 2-addr broadcast
        az[b] = fmaf(Uz_r[q*4+0], hv.x, az[b]); az[b] = fmaf(Uz_r[q*4+1], hv.y, az[b]);
        az[b] = fmaf(Uz_r[q*4+2], hv.z, az[b]); az[b] = fmaf(Uz_r[q*4+3], hv.w, az[b]);
        ar[b] = fmaf(Ur_r[q*4+0], hv.x, ar[b]); ar[b] = fmaf(Ur_r[q*4+1], hv.y, ar[b]);
        ar[b] = fmaf(Ur_r[q*4+2], hv.z, ar[b]); ar[b] = fmaf(Ur_r[q*4+3], hv.w, ar[b]);
        ah[b] = fmaf(Uh_r[q*4+0], hv.x, ah[b]); ah[b] = fmaf(Uh_r[q*4+1], hv.y, ah[b]);
        ah[b] = fmaf(Uh_r[q*4+2], hv.z, ah[b]); ah[b] = fmaf(Uh_r[q*4+3], hv.w, ah[b]);
      }
    }
    #pragma unroll
    for (int b = 0; b < 8; ++b) {
      red[0][b][hi][u] = az[b];
      red[1][b][hi][u] = ar[b];
      red[2][b][hi][u] = ah[b];
    }
    __syncthreads();
    float rz = 0.f, rr = 0.f, rh = 0.f;
    #pragma unroll
    for (int q = 0; q < 8; ++q) {
      rz += red[0][hi][q][u];
      rr += red[1][hi][q][u];
      rh += red[2][hi][q][u];
    }
    const int bg = b0 + hi;
    const float z = 1.f / (1.f + __expf(-(xz + rz + brz)));
    const float r = 1.f / (1.f + __expf(-(xr + rr + brr)));
    const float hh = tanhf(xh + r * (rh + brh));
    const float hold = hS[hi][u0 + u];
    const float hn = z * hold + (1.f - z) * hh;
    // h exchange: agent-scope atomic EXCHANGE executes AT the LLC.
    // Returning form (old pinned) => vmcnt ack means "applied at LLC".
    {
      float oldv = __hip_atomic_exchange(
          hb + ((size_t)(s & 1) * BB + bg) * NU + u0 + u, hn,
          __ATOMIC_RELAXED, __HIP_MEMORY_SCOPE_AGENT);
      asm volatile("" :: "v"(oldv));
    }
    if (s == TT - 1) {
      out[((size_t)bg * TT + t) * 1024 + (size_t)dir * NU + u0 + u] = hn;
      state[(size_t)bg * 1024 + (size_t)dir * NU + u0 + u] = hn;
    } else {
      // barrier: every wave's exchange RMW has RETURNED (= applied at LLC).
      __syncthreads();
      // signal: relaxed flag RMW (LLC) - issued strictly after all h RMWs done.
      if (tid == 0) {
        __hip_atomic_exchange(flags + ublk, s + 1,
                              __ATOMIC_RELAXED, __HIP_MEMORY_SCOPE_AGENT);
      }
      // ---- poll window: independent work whose latency hides here ----
      __builtin_nontemporal_store(
          hn, out + ((size_t)bg * TT + t) * 1024 + (size_t)dir * NU + u0 + u);
      {
        const int tn = dir ? (TT - 2 - s) : (s + 1);
        const float* xp = xwd + ((size_t)tn * BB + b0 + hi) * G3 + u0 + u;
        xz = xp[0]; xr = xp[512]; xh = xp[1024];
      }
      // wave 0: poll all 16 member flags (one coalesced 64B load per round)
      if (tid < 64) {
        const int target = s + 1;
        int f = target;
        for (;;) {
          if (tid < 16)
            f = __hip_atomic_load(flags + tid, __ATOMIC_RELAXED,
                                  __HIP_MEMORY_SCOPE_AGENT);
          if (__all(f >= target)) break;
          __builtin_amdgcn_s_sleep(1);
        }
      }
      __syncthreads();
      // reload h for our 8 batches, all 512 units (16 KB): 8 x u64 LLC loads
      const uint64_t* hsrc = (const uint64_t*)(hb + (size_t)(s & 1) * BB * NU);
      #pragma unroll
      for (int j = 0; j < 8; ++j) {
        const int fi = tid + j * 256;          // u64 index in [0,2048)
        const int bl = fi >> 8;                // local batch 0..7
        const int k2 = fi & 255;               // u64 within row
        uint64_t v = __hip_atomic_load(hsrc + ((size_t)(b0 + bl) << 8) + k2,
                                       __ATOMIC_RELAXED, __HIP_MEMORY_SCOPE_AGENT);
        *(uint64_t*)&hS[bl][k2 * 2] = v;
      }
      __syncthreads();
    }
  }
}

extern "C" void kernel_launch(void* const* d_in, const int* in_sizes, int n_in,
                              void* d_out, int out_size, void* d_ws, size_t ws_size,
                              hipStream_t stream) {
  (void)in_sizes; (void)n_in; (void)out_size; (void)ws_size;
  const int*   tokens = (const int*)d_in[0];
  const float* emb    = (const float*)d_in[1];
  const float* Wf     = (const float*)d_in[2];
  const float* Uf     = (const float*)d_in[3];
  const float* bf     = (const float*)d_in[4];
  const float* Wb     = (const float*)d_in[5];
  const float* Ub     = (const float*)d_in[6];
  const float* bb     = (const float*)d_in[7];
  float* ws = (float*)d_ws;
  float* xw = ws;
  float* hb = ws + XW_FLOATS;
  int*   ctr = (int*)(hb + HB_FLOATS);
  float* out = (float*)d_out;
  float* state = out + (size_t)BB * TT * 1024;

  hipMemsetAsync(ctr, 0, 16 * 32 * sizeof(int), stream);
  hipLaunchKernelGGL(k_input_gemm, dim3(24, 512, 2), dim3(256), 0, stream,
                     tokens, emb, Wf, bf, Wb, bb, xw);
  hipLaunchKernelGGL(k_gru, dim3(256), dim3(256), 0, stream,
                     xw, Uf, Ub, bf, bb, hb, ctr, out, state);
}

// Round 7
// 6137.341 us; speedup vs baseline: 1.3173x; 1.3173x over previous
//
#include <hip/hip_runtime.h>
#include <math.h>
#include <stdint.h>

#define TT   512
#define BB   64
#define EMBD 300
#define NU   512
#define G3   1536   // 3*UNITS

static constexpr size_t XW_FLOATS = (size_t)2 * TT * BB * G3;   // 100,663,296
static constexpr size_t HB_FLOATS = (size_t)2 * 2 * BB * NU;    //     131,072

// ------------- embedding gather + input GEMM: xw[dir][t][b][c] -------------
__global__ __launch_bounds__(256) void k_input_gemm(
    const int* __restrict__ tokens, const float* __restrict__ emb,
    const float* __restrict__ Wf, const float* __restrict__ bf,
    const float* __restrict__ Wb, const float* __restrict__ bb,
    float* __restrict__ xw) {
  __shared__ float As[8][72];   // [k][b]
  __shared__ float Bs[8][64];   // [k][n]
  __shared__ int tok[64];
  const int t = blockIdx.y;
  const int n0 = blockIdx.x * 64;
  const int dir = blockIdx.z;
  const float* W = dir ? Wb : Wf;
  const float* bias = dir ? bb : bf;           // row 0 = input bias
  float* out = xw + (size_t)dir * TT * BB * G3;
  const int tid = threadIdx.x;
  if (tid < 64) tok[tid] = tokens[(size_t)tid * TT + t];
  __syncthreads();
  const int tx = tid & 15, ty = tid >> 4;
  float4 c0 = {0,0,0,0}, c1 = {0,0,0,0}, c2 = {0,0,0,0}, c3 = {0,0,0,0};
  for (int kc = 0; kc < 38; ++kc) {
    const int k0 = kc * 8;
    if (tid < 128) {
      int kb = tid >> 4, nq = (tid & 15) * 4;
      float4 v = {0,0,0,0};
      if (k0 + kb < EMBD) v = *(const float4*)(W + (size_t)(k0 + kb) * G3 + n0 + nq);
      *(float4*)&Bs[kb][nq] = v;
    } else {
      int th = tid - 128;
      int b = th >> 1, kh = (th & 1) * 4;
      float4 v = {0,0,0,0};
      if (k0 + kh + 4 <= EMBD) v = *(const float4*)(emb + (size_t)tok[b] * EMBD + k0 + kh);
      As[kh + 0][b] = v.x; As[kh + 1][b] = v.y; As[kh + 2][b] = v.z; As[kh + 3][b] = v.w;
    }
    __syncthreads();
    #pragma unroll
    for (int kb = 0; kb < 8; ++kb) {
      float4 bv = *(const float4*)&Bs[kb][tx * 4];
      float4 av = *(const float4*)&As[kb][ty * 4];
      c0.x = fmaf(av.x, bv.x, c0.x); c0.y = fmaf(av.x, bv.y, c0.y);
      c0.z = fmaf(av.x, bv.z, c0.z); c0.w = fmaf(av.x, bv.w, c0.w);
      c1.x = fmaf(av.y, bv.x, c1.x); c1.y = fmaf(av.y, bv.y, c1.y);
      c1.z = fmaf(av.y, bv.z, c1.z); c1.w = fmaf(av.y, bv.w, c1.w);
      c2.x = fmaf(av.z, bv.x, c2.x); c2.y = fmaf(av.z, bv.y, c2.y);
      c2.z = fmaf(av.z, bv.z, c2.z); c2.w = fmaf(av.z, bv.w, c2.w);
      c3.x = fmaf(av.w, bv.x, c3.x); c3.y = fmaf(av.w, bv.y, c3.y);
      c3.z = fmaf(av.w, bv.z, c3.z); c3.w = fmaf(av.w, bv.w, c3.w);
    }
    __syncthreads();
  }
  float4 bi = *(const float4*)(bias + n0 + tx * 4);
  size_t base = ((size_t)t * BB + (size_t)ty * 4) * G3 + n0 + tx * 4;
  float4 o;
  o.x = c0.x + bi.x; o.y = c0.y + bi.y; o.z = c0.z + bi.z; o.w = c0.w + bi.w;
  *(float4*)(out + base) = o;
  o.x = c1.x + bi.x; o.y = c1.y + bi.y; o.z = c1.z + bi.z; o.w = c1.w + bi.w;
  *(float4*)(out + base + G3) = o;
  o.x = c2.x + bi.x; o.y = c2.y + bi.y; o.z = c2.z + bi.z; o.w = c2.w + bi.w;
  *(float4*)(out + base + 2 * G3) = o;
  o.x = c3.x + bi.x; o.y = c3.y + bi.y; o.z = c3.z + bi.z; o.w = c3.w + bi.w;
  *(float4*)(out + base + 3 * G3) = o;
}

// --------------------------- persistent GRU scan v8 ---------------------------
// Topology & sync = v1 EXACTLY (passed twice: release fetch_add chain on one
// counter per 16-block group; no XCD awareness, no s_getreg, no new machinery).
// Changes vs v1, all individually proven in passing runs:
//  * 512 threads/block: 16 ksplits x 32k (v2/v4-proven split tree) -> 768
//    FMA/thread instead of 1536; U slice 96 VGPRs; 8 waves/CU so ds_read
//    latency overlaps across waves.
//  * poll busy-loop with NO s_sleep: detect latency = one LLC load round-trip
//    instead of sleep-quantized (v5 showed detect+skew dominates, not wbl2).
//  * out-store + next-step xw prefetch in the poll window (v5-proven): the
//    pre-release drain covers only the h stores.
//  * h reload as u64 agent loads (v5-proven), 4 per thread.
__global__ __launch_bounds__(512, 2) void k_gru(
    const float* __restrict__ xw,
    const float* __restrict__ Uf, const float* __restrict__ Ub,
    const float* __restrict__ bf, const float* __restrict__ bb,
    float* __restrict__ hbuf, int* __restrict__ ctr,
    float* __restrict__ out, float* __restrict__ state) {
  __shared__ float hS[8][NU];           // 16KB: h for this block's 8 batches
  __shared__ float red[3][8][16][32];   // 48KB: [gate][batch][ksplit][unit]
  const int wg = blockIdx.x;
  const int dir = wg >> 7;
  const int bblk = (wg >> 4) & 7;
  const int ublk = wg & 15;
  const int u0 = ublk * 32, b0 = bblk * 8;
  const int gid = dir * 8 + bblk;
  int* gctr = ctr + gid * 32;          // 128B-spaced counters (v1 layout)
  const int tid = threadIdx.x;
  const int u  = tid & 31;             // unit within slice (compute phase)
  const int ks = tid >> 5;             // ksplit 0..15 (32 k each)
  const int kb0 = ks * 32;
  const float* xwd = xw + (size_t)dir * TT * BB * G3;
  const float* U = dir ? Ub : Uf;      // [k][c], c = gate*512 + unit
  const float* br = (dir ? bb : bf) + G3;   // row 1 = recurrent bias
  float* hb = hbuf + (size_t)dir * 2 * BB * NU;

  // ---- preload U slice (k in [kb0,kb0+32), col u0+u) into regs, then PIN ----
  float Uz_r[32], Ur_r[32], Uh_r[32];
  #pragma unroll
  for (int kk = 0; kk < 32; ++kk) {
    const float* row = U + (size_t)(kb0 + kk) * G3 + u0 + u;
    Uz_r[kk] = row[0];
    Ur_r[kk] = row[512];
    Uh_r[kk] = row[1024];
  }
  #pragma unroll
  for (int kk = 0; kk < 32; ++kk) {
    asm volatile("" : "+v"(Uz_r[kk]), "+v"(Ur_r[kk]), "+v"(Uh_r[kk]));
  }

  // epilogue identity (tid < 256): same (batch, unit) map as v1
  const int eb = (tid >> 5) & 7, eu = tid & 31;
  const int bg = b0 + eb;
  const float brz = br[u0 + eu], brr = br[512 + u0 + eu], brh = br[1024 + u0 + eu];
  float xz = 0.f, xr = 0.f, xh = 0.f;
  if (tid < 256) {
    const int t0 = dir ? (TT - 1) : 0;
    const float* xp = xwd + ((size_t)t0 * BB + bg) * G3 + u0 + eu;
    xz = xp[0]; xr = xp[512]; xh = xp[1024];
  }

  float* hflat = &hS[0][0];
  #pragma unroll
  for (int j = 0; j < 8; ++j) hflat[tid + j * 512] = 0.f;   // h0 = 0
  __syncthreads();

  for (int s = 0; s < TT; ++s) {
    const int t = dir ? (TT - 1 - s) : s;
    float az[8], ar[8], ah[8];
    #pragma unroll
    for (int b = 0; b < 8; ++b) { az[b] = 0.f; ar[b] = 0.f; ah[b] = 0.f; }
    #pragma unroll
    for (int q = 0; q < 8; ++q) {
      #pragma unroll
      for (int b = 0; b < 8; ++b) {
        float4 hv = *(const float4*)&hS[b][kb0 + q * 4];   // 2-addr broadcast
        az[b] = fmaf(Uz_r[q*4+0], hv.x, az[b]); az[b] = fmaf(Uz_r[q*4+1], hv.y, az[b]);
        az[b] = fmaf(Uz_r[q*4+2], hv.z, az[b]); az[b] = fmaf(Uz_r[q*4+3], hv.w, az[b]);
        ar[b] = fmaf(Ur_r[q*4+0], hv.x, ar[b]); ar[b] = fmaf(Ur_r[q*4+1], hv.y, ar[b]);
        ar[b] = fmaf(Ur_r[q*4+2], hv.z, ar[b]); ar[b] = fmaf(Ur_r[q*4+3], hv.w, ar[b]);
        ah[b] = fmaf(Uh_r[q*4+0], hv.x, ah[b]); ah[b] = fmaf(Uh_r[q*4+1], hv.y, ah[b]);
        ah[b] = fmaf(Uh_r[q*4+2], hv.z, ah[b]); ah[b] = fmaf(Uh_r[q*4+3], hv.w, ah[b]);
      }
    }
    #pragma unroll
    for (int b = 0; b < 8; ++b) {
      red[0][b][ks][u] = az[b];
      red[1][b][ks][u] = ar[b];
      red[2][b][ks][u] = ah[b];
    }
    __syncthreads();
    float hn = 0.f;
    if (tid < 256) {
      float rz = 0.f, rr = 0.f, rh = 0.f;
      #pragma unroll
      for (int q2 = 0; q2 < 16; ++q2) {
        rz += red[0][eb][q2][eu];
        rr += red[1][eb][q2][eu];
        rh += red[2][eb][q2][eu];
      }
      const float z  = 1.f / (1.f + __expf(-(xz + rz + brz)));
      const float r  = 1.f / (1.f + __expf(-(xr + rr + brr)));
      const float hh = tanhf(xh + r * (rh + brh));
      const float hold = hS[eb][u0 + eu];
      hn = z * hold + (1.f - z) * hh;
      // h exchange: agent-scope (LLC-coherent) store (v1-proven path)
      __hip_atomic_store(hb + ((size_t)(s & 1) * BB + bg) * NU + u0 + eu, hn,
                         __ATOMIC_RELAXED, __HIP_MEMORY_SCOPE_AGENT);
    }
    if (s == TT - 1) {
      if (tid < 256) {
        out[((size_t)bg * TT + t) * 1024 + (size_t)dir * NU + u0 + eu] = hn;
        state[(size_t)bg * 1024 + (size_t)dir * NU + u0 + eu] = hn;
      }
    } else {
      // barrier: all h stores vmcnt-drained before the release
      __syncthreads();
      if (tid == 0) {
        // RELEASE: drains + wbl2 publishes this block's h, then the add lands
        __hip_atomic_fetch_add(gctr, 1, __ATOMIC_RELEASE,
                               __HIP_MEMORY_SCOPE_AGENT);
      }
      // ---- poll window: independent work whose latency hides here ----
      if (tid < 256) {
        out[((size_t)bg * TT + t) * 1024 + (size_t)dir * NU + u0 + eu] = hn;
        const int tn = dir ? (TT - 2 - s) : (s + 1);
        const float* xp = xwd + ((size_t)tn * BB + bg) * G3 + u0 + eu;
        xz = xp[0]; xr = xp[512]; xh = xp[1024];
      }
      if (tid == 0) {
        const int target = 16 * (s + 1);
        // busy poll, NO sleep: detect latency = one LLC load round-trip
        while (__hip_atomic_load(gctr, __ATOMIC_RELAXED,
                                 __HIP_MEMORY_SCOPE_AGENT) < target) {
        }
      }
      __syncthreads();
      // reload h for our 8 batches, all 512 units (16 KB): 4 x u64 LLC loads
      const uint64_t* hsrc = (const uint64_t*)(hb + (size_t)(s & 1) * BB * NU);
      #pragma unroll
      for (int j = 0; j < 4; ++j) {
        const int fi = tid + j * 512;          // u64 index in [0,2048)
        const int bl = fi >> 8;                // local batch 0..7
        const int k2 = fi & 255;               // u64 within row
        uint64_t v = __hip_atomic_load(hsrc + ((size_t)(b0 + bl) << 8) + k2,
                                       __ATOMIC_RELAXED, __HIP_MEMORY_SCOPE_AGENT);
        *(uint64_t*)&hS[bl][k2 * 2] = v;
      }
      __syncthreads();
    }
  }
}

extern "C" void kernel_launch(void* const* d_in, const int* in_sizes, int n_in,
                              void* d_out, int out_size, void* d_ws, size_t ws_size,
                              hipStream_t stream) {
  (void)in_sizes; (void)n_in; (void)out_size; (void)ws_size;
  const int*   tokens = (const int*)d_in[0];
  const float* emb    = (const float*)d_in[1];
  const float* Wf     = (const float*)d_in[2];
  const float* Uf     = (const float*)d_in[3];
  const float* bf     = (const float*)d_in[4];
  const float* Wb     = (const float*)d_in[5];
  const float* Ub     = (const float*)d_in[6];
  const float* bb     = (const float*)d_in[7];
  float* ws = (float*)d_ws;
  float* xw = ws;
  float* hb = ws + XW_FLOATS;
  int*   ctr = (int*)(hb + HB_FLOATS);
  float* out = (float*)d_out;
  float* state = out + (size_t)BB * TT * 1024;

  hipMemsetAsync(ctr, 0, 16 * 32 * sizeof(int), stream);
  hipLaunchKernelGGL(k_input_gemm, dim3(24, 512, 2), dim3(256), 0, stream,
                     tokens, emb, Wf, bf, Wb, bb, xw);
  hipLaunchKernelGGL(k_gru, dim3(256), dim3(512), 0, stream,
                     xw, Uf, Ub, bf, bb, hb, ctr, out, state);
}

// Round 8
// 6002.304 us; speedup vs baseline: 1.3469x; 1.0225x over previous
//
#include <hip/hip_runtime.h>
#include <math.h>
#include <stdint.h>

#define TT   512
#define BB   64
#define EMBD 300
#define NU   512
#define G3   1536   // 3*UNITS

static constexpr size_t XW_FLOATS = (size_t)2 * TT * BB * G3;   // 100,663,296
static constexpr size_t HB_FLOATS = (size_t)2 * 2 * BB * NU;    //     131,072

// ------------- embedding gather + input GEMM: xw[dir][t][b][c] -------------
__global__ __launch_bounds__(256) void k_input_gemm(
    const int* __restrict__ tokens, const float* __restrict__ emb,
    const float* __restrict__ Wf, const float* __restrict__ bf,
    const float* __restrict__ Wb, const float* __restrict__ bb,
    float* __restrict__ xw) {
  __shared__ float As[8][72];   // [k][b]
  __shared__ float Bs[8][64];   // [k][n]
  __shared__ int tok[64];
  const int t = blockIdx.y;
  const int n0 = blockIdx.x * 64;
  const int dir = blockIdx.z;
  const float* W = dir ? Wb : Wf;
  const float* bias = dir ? bb : bf;           // row 0 = input bias
  float* out = xw + (size_t)dir * TT * BB * G3;
  const int tid = threadIdx.x;
  if (tid < 64) tok[tid] = tokens[(size_t)tid * TT + t];
  __syncthreads();
  const int tx = tid & 15, ty = tid >> 4;
  float4 c0 = {0,0,0,0}, c1 = {0,0,0,0}, c2 = {0,0,0,0}, c3 = {0,0,0,0};
  for (int kc = 0; kc < 38; ++kc) {
    const int k0 = kc * 8;
    if (tid < 128) {
      int kb = tid >> 4, nq = (tid & 15) * 4;
      float4 v = {0,0,0,0};
      if (k0 + kb < EMBD) v = *(const float4*)(W + (size_t)(k0 + kb) * G3 + n0 + nq);
      *(float4*)&Bs[kb][nq] = v;
    } else {
      int th = tid - 128;
      int b = th >> 1, kh = (th & 1) * 4;
      float4 v = {0,0,0,0};
      if (k0 + kh + 4 <= EMBD) v = *(const float4*)(emb + (size_t)tok[b] * EMBD + k0 + kh);
      As[kh + 0][b] = v.x; As[kh + 1][b] = v.y; As[kh + 2][b] = v.z; As[kh + 3][b] = v.w;
    }
    __syncthreads();
    #pragma unroll
    for (int kb = 0; kb < 8; ++kb) {
      float4 bv = *(const float4*)&Bs[kb][tx * 4];
      float4 av = *(const float4*)&As[kb][ty * 4];
      c0.x = fmaf(av.x, bv.x, c0.x); c0.y = fmaf(av.x, bv.y, c0.y);
      c0.z = fmaf(av.x, bv.z, c0.z); c0.w = fmaf(av.x, bv.w, c0.w);
      c1.x = fmaf(av.y, bv.x, c1.x); c1.y = fmaf(av.y, bv.y, c1.y);
      c1.z = fmaf(av.y, bv.z, c1.z); c1.w = fmaf(av.y, bv.w, c1.w);
      c2.x = fmaf(av.z, bv.x, c2.x); c2.y = fmaf(av.z, bv.y, c2.y);
      c2.z = fmaf(av.z, bv.z, c2.z); c2.w = fmaf(av.z, bv.w, c2.w);
      c3.x = fmaf(av.w, bv.x, c3.x); c3.y = fmaf(av.w, bv.y, c3.y);
      c3.z = fmaf(av.w, bv.z, c3.z); c3.w = fmaf(av.w, bv.w, c3.w);
    }
    __syncthreads();
  }
  float4 bi = *(const float4*)(bias + n0 + tx * 4);
  size_t base = ((size_t)t * BB + (size_t)ty * 4) * G3 + n0 + tx * 4;
  float4 o;
  o.x = c0.x + bi.x; o.y = c0.y + bi.y; o.z = c0.z + bi.z; o.w = c0.w + bi.w;
  *(float4*)(out + base) = o;
  o.x = c1.x + bi.x; o.y = c1.y + bi.y; o.z = c1.z + bi.z; o.w = c1.w + bi.w;
  *(float4*)(out + base + G3) = o;
  o.x = c2.x + bi.x; o.y = c2.y + bi.y; o.z = c2.z + bi.z; o.w = c2.w + bi.w;
  *(float4*)(out + base + 2 * G3) = o;
  o.x = c3.x + bi.x; o.y = c3.y + bi.y; o.z = c3.z + bi.z; o.w = c3.w + bi.w;
  *(float4*)(out + base + 3 * G3) = o;
}

// --------------------------- persistent GRU scan v9 ---------------------------
// = v8 (passed, 5.53ms k_gru) with ONE change: U made GENUINELY
// register-resident. Evidence: v8 VGPR_Count=80 < 96 U values/thread (v1:
// 132 < 192) => allocator was rematerializing U loads from L2 inside the FMA
// loop every step; the once-before-loop pin does not prevent remat. Fix:
// "+v" pin INSIDE the step loop — a read-write asm operand each iteration
// makes reload-from-memory illegal, forcing true VGPR residency.
// launch_bounds(512,1) lifts the 128-VGPR cap; expected ~160-200 VGPRs ->
// still 2 waves/SIMD -> 2 blocks/CU (LDS 64KB), same occupancy as v8.
__global__ __launch_bounds__(512, 1) void k_gru(
    const float* __restrict__ xw,
    const float* __restrict__ Uf, const float* __restrict__ Ub,
    const float* __restrict__ bf, const float* __restrict__ bb,
    float* __restrict__ hbuf, int* __restrict__ ctr,
    float* __restrict__ out, float* __restrict__ state) {
  __shared__ float hS[8][NU];           // 16KB: h for this block's 8 batches
  __shared__ float red[3][8][16][32];   // 48KB: [gate][batch][ksplit][unit]
  const int wg = blockIdx.x;
  const int dir = wg >> 7;
  const int bblk = (wg >> 4) & 7;
  const int ublk = wg & 15;
  const int u0 = ublk * 32, b0 = bblk * 8;
  const int gid = dir * 8 + bblk;
  int* gctr = ctr + gid * 32;          // 128B-spaced counters (v1 layout)
  const int tid = threadIdx.x;
  const int u  = tid & 31;             // unit within slice (compute phase)
  const int ks = tid >> 5;             // ksplit 0..15 (32 k each)
  const int kb0 = ks * 32;
  const float* xwd = xw + (size_t)dir * TT * BB * G3;
  const float* U = dir ? Ub : Uf;      // [k][c], c = gate*512 + unit
  const float* br = (dir ? bb : bf) + G3;   // row 1 = recurrent bias
  float* hb = hbuf + (size_t)dir * 2 * BB * NU;

  // ---- preload U slice (k in [kb0,kb0+32), col u0+u) into regs ----
  float Uz_r[32], Ur_r[32], Uh_r[32];
  #pragma unroll
  for (int kk = 0; kk < 32; ++kk) {
    const float* row = U + (size_t)(kb0 + kk) * G3 + u0 + u;
    Uz_r[kk] = row[0];
    Ur_r[kk] = row[512];
    Uh_r[kk] = row[1024];
  }

  // epilogue identity (tid < 256): same (batch, unit) map as v1
  const int eb = (tid >> 5) & 7, eu = tid & 31;
  const int bg = b0 + eb;
  const float brz = br[u0 + eu], brr = br[512 + u0 + eu], brh = br[1024 + u0 + eu];
  float xz = 0.f, xr = 0.f, xh = 0.f;
  if (tid < 256) {
    const int t0 = dir ? (TT - 1) : 0;
    const float* xp = xwd + ((size_t)t0 * BB + bg) * G3 + u0 + eu;
    xz = xp[0]; xr = xp[512]; xh = xp[1024];
  }

  float* hflat = &hS[0][0];
  #pragma unroll
  for (int j = 0; j < 8; ++j) hflat[tid + j * 512] = 0.f;   // h0 = 0
  __syncthreads();

  for (int s = 0; s < TT; ++s) {
    // ---- PIN: read-write asm each iteration => remat-from-memory illegal.
    #define PIN8(A, i) asm volatile("" : \
        "+v"(A[(i)+0]), "+v"(A[(i)+1]), "+v"(A[(i)+2]), "+v"(A[(i)+3]), \
        "+v"(A[(i)+4]), "+v"(A[(i)+5]), "+v"(A[(i)+6]), "+v"(A[(i)+7]))
    PIN8(Uz_r, 0); PIN8(Uz_r, 8); PIN8(Uz_r, 16); PIN8(Uz_r, 24);
    PIN8(Ur_r, 0); PIN8(Ur_r, 8); PIN8(Ur_r, 16); PIN8(Ur_r, 24);
    PIN8(Uh_r, 0); PIN8(Uh_r, 8); PIN8(Uh_r, 16); PIN8(Uh_r, 24);
    #undef PIN8

    const int t = dir ? (TT - 1 - s) : s;
    float az[8], ar[8], ah[8];
    #pragma unroll
    for (int b = 0; b < 8; ++b) { az[b] = 0.f; ar[b] = 0.f; ah[b] = 0.f; }
    #pragma unroll
    for (int q = 0; q < 8; ++q) {
      #pragma unroll
      for (int b = 0; b < 8; ++b) {
        float4 hv = *(const float4*)&hS[b][kb0 + q * 4];   // 2-addr broadcast
        az[b] = fmaf(Uz_r[q*4+0], hv.x, az[b]); az[b] = fmaf(Uz_r[q*4+1], hv.y, az[b]);
        az[b] = fmaf(Uz_r[q*4+2], hv.z, az[b]); az[b] = fmaf(Uz_r[q*4+3], hv.w, az[b]);
        ar[b] = fmaf(Ur_r[q*4+0], hv.x, ar[b]); ar[b] = fmaf(Ur_r[q*4+1], hv.y, ar[b]);
        ar[b] = fmaf(Ur_r[q*4+2], hv.z, ar[b]); ar[b] = fmaf(Ur_r[q*4+3], hv.w, ar[b]);
        ah[b] = fmaf(Uh_r[q*4+0], hv.x, ah[b]); ah[b] = fmaf(Uh_r[q*4+1], hv.y, ah[b]);
        ah[b] = fmaf(Uh_r[q*4+2], hv.z, ah[b]); ah[b] = fmaf(Uh_r[q*4+3], hv.w, ah[b]);
      }
    }
    #pragma unroll
    for (int b = 0; b < 8; ++b) {
      red[0][b][ks][u] = az[b];
      red[1][b][ks][u] = ar[b];
      red[2][b][ks][u] = ah[b];
    }
    __syncthreads();
    float hn = 0.f;
    if (tid < 256) {
      float rz = 0.f, rr = 0.f, rh = 0.f;
      #pragma unroll
      for (int q2 = 0; q2 < 16; ++q2) {
        rz += red[0][eb][q2][eu];
        rr += red[1][eb][q2][eu];
        rh += red[2][eb][q2][eu];
      }
      const float z  = 1.f / (1.f + __expf(-(xz + rz + brz)));
      const float r  = 1.f / (1.f + __expf(-(xr + rr + brr)));
      const float hh = tanhf(xh + r * (rh + brh));
      const float hold = hS[eb][u0 + eu];
      hn = z * hold + (1.f - z) * hh;
      // h exchange: agent-scope (LLC-coherent) store (v1-proven path)
      __hip_atomic_store(hb + ((size_t)(s & 1) * BB + bg) * NU + u0 + eu, hn,
                         __ATOMIC_RELAXED, __HIP_MEMORY_SCOPE_AGENT);
    }
    if (s == TT - 1) {
      if (tid < 256) {
        out[((size_t)bg * TT + t) * 1024 + (size_t)dir * NU + u0 + eu] = hn;
        state[(size_t)bg * 1024 + (size_t)dir * NU + u0 + eu] = hn;
      }
    } else {
      // barrier: all h stores vmcnt-drained before the release
      __syncthreads();
      if (tid == 0) {
        // RELEASE: drains + wbl2 publishes this block's h, then the add lands
        __hip_atomic_fetch_add(gctr, 1, __ATOMIC_RELEASE,
                               __HIP_MEMORY_SCOPE_AGENT);
      }
      // ---- poll window: independent work whose latency hides here ----
      if (tid < 256) {
        out[((size_t)bg * TT + t) * 1024 + (size_t)dir * NU + u0 + eu] = hn;
        const int tn = dir ? (TT - 2 - s) : (s + 1);
        const float* xp = xwd + ((size_t)tn * BB + bg) * G3 + u0 + eu;
        xz = xp[0]; xr = xp[512]; xh = xp[1024];
      }
      if (tid == 0) {
        const int target = 16 * (s + 1);
        // busy poll, NO sleep: detect latency = one LLC load round-trip
        while (__hip_atomic_load(gctr, __ATOMIC_RELAXED,
                                 __HIP_MEMORY_SCOPE_AGENT) < target) {
        }
      }
      __syncthreads();
      // reload h for our 8 batches, all 512 units (16 KB): 4 x u64 LLC loads
      const uint64_t* hsrc = (const uint64_t*)(hb + (size_t)(s & 1) * BB * NU);
      #pragma unroll
      for (int j = 0; j < 4; ++j) {
        const int fi = tid + j * 512;          // u64 index in [0,2048)
        const int bl = fi >> 8;                // local batch 0..7
        const int k2 = fi & 255;               // u64 within row
        uint64_t v = __hip_atomic_load(hsrc + ((size_t)(b0 + bl) << 8) + k2,
                                       __ATOMIC_RELAXED, __HIP_MEMORY_SCOPE_AGENT);
        *(uint64_t*)&hS[bl][k2 * 2] = v;
      }
      __syncthreads();
    }
  }
}

extern "C" void kernel_launch(void* const* d_in, const int* in_sizes, int n_in,
                              void* d_out, int out_size, void* d_ws, size_t ws_size,
                              hipStream_t stream) {
  (void)in_sizes; (void)n_in; (void)out_size; (void)ws_size;
  const int*   tokens = (const int*)d_in[0];
  const float* emb    = (const float*)d_in[1];
  const float* Wf     = (const float*)d_in[2];
  const float* Uf     = (const float*)d_in[3];
  const float* bf     = (const float*)d_in[4];
  const float* Wb     = (const float*)d_in[5];
  const float* Ub     = (const float*)d_in[6];
  const float* bb     = (const float*)d_in[7];
  float* ws = (float*)d_ws;
  float* xw = ws;
  float* hb = ws + XW_FLOATS;
  int*   ctr = (int*)(hb + HB_FLOATS);
  float* out = (float*)d_out;
  float* state = out + (size_t)BB * TT * 1024;

  hipMemsetAsync(ctr, 0, 16 * 32 * sizeof(int), stream);
  hipLaunchKernelGGL(k_input_gemm, dim3(24, 512, 2), dim3(256), 0, stream,
                     tokens, emb, Wf, bf, Wb, bb, xw);
  hipLaunchKernelGGL(k_gru, dim3(256), dim3(512), 0, stream,
                     xw, Uf, Ub, bf, bb, hb, ctr, out, state);
}